// Round 5
// baseline (184.116 us; speedup 1.0000x reference)
//
#include <hip/hip_runtime.h>
#include <hip/hip_bf16.h>

// Fused MHA fwd: out = softmax(scale*Q@K^T + bias) @ V
// B=2 H=16 S=2048 D=64, fp32 in/out, bf16 MFMA.
// R5: S^T trick — compute S^T = K*Q^T (operand swap, identical LDS reads),
// so each lane holds P for its own query. V is staged with a fixed row
// permutation phi (baked into prep) such that the packed exp2 results ARE the
// PV A-fragments in-register: the entire P LDS round-trip (16 ds_write_b16 +
// 2 ds_read_b128 per wave-tile) vanishes. Bias becomes 4 float4 loads.
// LDS pipe per wave-tile: 310 -> 192 cyc (the real R4 bottleneck).

#define SEQ 2048
#define DH  64
#define BHN 32
#define LOG2E 1.44269504088896f

typedef __attribute__((ext_vector_type(8))) short bf16x8;
typedef __attribute__((ext_vector_type(4))) float f32x4;
typedef __attribute__((ext_vector_type(8))) short short8v;

__device__ inline short f2b(float x) {
    union { float f; unsigned u; } v; v.f = x;
    unsigned r = v.u + 0x7fff + ((v.u >> 16) & 1);
    return (short)(r >> 16);
}

__device__ inline void gl_lds16(const void* g, void* l) {
    __builtin_amdgcn_global_load_lds(
        (const __attribute__((address_space(1))) void*)g,
        (__attribute__((address_space(3))) void*)l, 16, 0, 0);
}

// phi: PV A-frag slot rho' -> logical key offset within the 64-tile.
// phi(r) = 32*(r>>5) + 16*((r>>2)&1) + 4*((r>>3)&3) + (r&3)
__device__ __host__ inline int phi(int r) {
    return 32 * (r >> 5) + 16 * ((r >> 2) & 1) + 4 * ((r >> 3) & 3) + (r & 3);
}

// ---- fused prep: K fp32->bf16 (identity) + V fp32->bf16 transposed with
// phi-permuted columns within each 64-column block ----
__global__ __launch_bounds__(256)
void prep_kv(const float* __restrict__ K, const float* __restrict__ V,
             short* __restrict__ Kb, short* __restrict__ Vt) {
    __shared__ short t[64 * 72];
    const int tid = threadIdx.x;
    const int bh = blockIdx.x >> 5, st = blockIdx.x & 31, s0 = st * 64;

    {
        const float* Kp = K + ((size_t)bh * SEQ + s0) * DH;
        short* Ko = Kb + ((size_t)bh * SEQ + s0) * DH;
        #pragma unroll
        for (int i = 0; i < 2; ++i) {
            size_t o = (size_t)(tid + i * 256) * 8;
            f32x4 a = *(const f32x4*)(Kp + o);
            f32x4 b = *(const f32x4*)(Kp + o + 4);
            short8v s;
            #pragma unroll
            for (int j = 0; j < 4; ++j) { s[j] = f2b(a[j]); s[4 + j] = f2b(b[j]); }
            *(short8v*)(Ko + o) = s;
        }
    }

    // stage V rows (s-major) into LDS
    const float* Vb = V + (size_t)bh * SEQ * DH + (size_t)s0 * DH;
    #pragma unroll
    for (int i = 0; i < 4; ++i) {
        int c = tid + i * 256, s = c >> 4, c4 = c & 15;
        f32x4 v = *(const f32x4*)(Vb + s * DH + c4 * 4);
        #pragma unroll
        for (int j = 0; j < 4; ++j) t[s * 72 + c4 * 4 + j] = f2b(v[j]);
    }
    __syncthreads();
    // write Vt[bh][d][s0 + rho'] = V[s0 + phi(rho')][d]
    const int d = tid >> 2, part = tid & 3;
    short* outp = Vt + (size_t)bh * DH * SEQ + (size_t)d * SEQ + s0 + part * 16;
    #pragma unroll
    for (int h = 0; h < 2; ++h) {
        short8v w;
        #pragma unroll
        for (int u = 0; u < 8; ++u) {
            int rho = part * 16 + h * 8 + u;
            w[u] = t[phi(rho) * 72 + d];
        }
        *(short8v*)(outp + h * 8) = w;
    }
}

// ---- main fused attention ----
__global__ __launch_bounds__(256, 4)
void mha_main(const float* __restrict__ Q, const float* __restrict__ Bias,
              const short* __restrict__ Kb, const short* __restrict__ Vt,
              float* __restrict__ Out)
{
    // double-buffered K/V tiles as DISTINCT objects (alias precision)
    __shared__ short ka[64 * DH];
    __shared__ short kbuf[64 * DH];
    __shared__ short va[64 * DH];
    __shared__ short vbuf[64 * DH];

    const int tid = threadIdx.x, lane = tid & 63, wave = tid >> 6;
    const int l15 = lane & 15, l4 = lane >> 4;
    const int qb = blockIdx.x & 31, bh = blockIdx.x >> 5;
    const int q0 = qb * 64;

    const float* Qb = Q + (size_t)bh * SEQ * DH;
    const short* Kh = Kb + (size_t)bh * SEQ * DH;
    const short* Vh = Vt + (size_t)bh * DH * SEQ;
    float* Ob = Out + (size_t)bh * SEQ * DH;

    // Q fragments (per-lane: query=l15, d=ks*32+l4*8+j), pre-scaled by LOG2E/8
    bf16x8 qf[2];
    {
        const float* qp = Qb + (size_t)(q0 + wave * 16 + l15) * DH;
        #pragma unroll
        for (int ks = 0; ks < 2; ++ks) {
            short tmp[8];
            #pragma unroll
            for (int j = 0; j < 8; ++j) tmp[j] = f2b(qp[ks * 32 + l4 * 8 + j] * (0.125f * LOG2E));
            qf[ks] = *reinterpret_cast<bf16x8*>(tmp);
        }
    }

    f32x4 o_acc[4];
    #pragma unroll
    for (int dt = 0; dt < 4; ++dt) o_acc[dt] = f32x4{0.f, 0.f, 0.f, 0.f};
    float l_part = 0.f;   // per-lane partial sum for query l15

    // staging descriptors: lane's fixed LDS slot, swizzled global chunk
    const short *kg0, *kg1, *vg0, *vg1;
    int off0, off1;
    {
        int s0_ = wave * 64 + lane, r0 = s0_ >> 3, c0 = s0_ & 7, g0 = c0 ^ (r0 & 7);
        int s1_ = 256 + wave * 64 + lane, r1 = s1_ >> 3, c1 = s1_ & 7, g1 = c1 ^ (r1 & 7);
        kg0 = Kh + (size_t)r0 * DH + g0 * 8;
        vg0 = Vh + (size_t)r0 * SEQ + g0 * 8;
        kg1 = Kh + (size_t)r1 * DH + g1 * 8;
        vg1 = Vh + (size_t)r1 * SEQ + g1 * 8;
        off0 = (wave * 64) * 8;
        off1 = (256 + wave * 64) * 8;
    }
    // bias base: row = query (l15), cols k0 + nt*16 + l4*4 + r  -> float4
    const float* bp0 = Bias + (size_t)(q0 + wave * 16 + l15) * SEQ + l4 * 4;
    const int swz = l15 & 7;

    // preamble: stage tile 0 into ka/va
    gl_lds16(kg0, ka + off0);
    gl_lds16(kg1, ka + off1);
    gl_lds16(vg0, va + off0);
    gl_lds16(vg1, va + off1);

    auto tile = [&](int kt, const short* kc, const short* vc,
                    short* knx, short* vnx) {
        // 1) bias loads (4x float4, in flight until softmax)
        f32x4 bv[4];
        const float* bp = bp0 + kt * 64;
        #pragma unroll
        for (int nt = 0; nt < 4; ++nt)
            bv[nt] = *(const f32x4*)(bp + nt * 16);

        // 2) stage tile kt+1 into the other buffer
        const int kn = (kt + 1) & 31;
        gl_lds16(kg0 + (size_t)kn * 64 * DH, knx + off0);
        gl_lds16(kg1 + (size_t)kn * 64 * DH, knx + off1);
        gl_lds16(vg0 + kn * 64, vnx + off0);
        gl_lds16(vg1 + kn * 64, vnx + off1);

        // 3) retire only the 4 oldest (tile-kt staging); bias + next stay in flight
        asm volatile("s_waitcnt vmcnt(8)\n\ts_barrier" ::: "memory");

        // 4) S^T = K*Q^T: operands swapped; reads identical to QK^T form.
        //    Lane holds S^T[key=nt*16+l4*4+r][query=l15], log2-scaled.
        f32x4 sacc[4];
        #pragma unroll
        for (int nt = 0; nt < 4; ++nt) sacc[nt] = f32x4{0.f, 0.f, 0.f, 0.f};
        #pragma unroll
        for (int ks = 0; ks < 2; ++ks)
            #pragma unroll
            for (int nt = 0; nt < 4; ++nt) {
                int cc = (ks * 4 + l4) ^ swz;
                bf16x8 kf = *(const bf16x8*)&kc[(nt * 16 + l15) * DH + cc * 8];
                sacc[nt] = __builtin_amdgcn_mfma_f32_16x16x32_bf16(kf, qf[ks], sacc[nt], 0, 0, 0);
            }

        // 5) softmax in log2 domain; pack pairs -> PV A-frags in-register
        unsigned pk[4][2];
        #pragma unroll
        for (int nt = 0; nt < 4; ++nt) {
            float pv[4];
            #pragma unroll
            for (int r = 0; r < 4; ++r) {
                pv[r] = __builtin_amdgcn_exp2f(__builtin_fmaf(bv[nt][r], LOG2E, sacc[nt][r]));
                l_part += pv[r];
            }
            #pragma unroll
            for (int rp = 0; rp < 2; ++rp) {
                __hip_bfloat162 h2 = __float22bfloat162_rn(float2{pv[2 * rp], pv[2 * rp + 1]});
                pk[nt][rp] = *reinterpret_cast<unsigned*>(&h2);
            }
        }

        // 6) O += P @ V_staged (phi-permuted V makes pk the A-frags directly)
        #pragma unroll
        for (int ks = 0; ks < 2; ++ks) {
            union { bf16x8 v; unsigned u[4]; } af;
            af.u[0] = pk[2 * ks][0]; af.u[1] = pk[2 * ks][1];
            af.u[2] = pk[2 * ks + 1][0]; af.u[3] = pk[2 * ks + 1][1];
            #pragma unroll
            for (int dt = 0; dt < 4; ++dt) {
                int cc = (ks * 4 + l4) ^ swz;
                bf16x8 vf = *(const bf16x8*)&vc[(dt * 16 + l15) * DH + cc * 8];
                o_acc[dt] = __builtin_amdgcn_mfma_f32_16x16x32_bf16(af.v, vf, o_acc[dt], 0, 0, 0);
            }
        }

        // 7) all reads of current buffers consumed -> bare barrier
        asm volatile("s_barrier" ::: "memory");
    };

    for (int kt = 0; kt < SEQ / 64; kt += 2) {
        tile(kt,     ka,   va,   kbuf, vbuf);
        tile(kt + 1, kbuf, vbuf, ka,   va);
    }

    // l: full sum per query l15 (reduce across l4 groups), then fetch per-row
    l_part += __shfl_xor(l_part, 16, 64);
    l_part += __shfl_xor(l_part, 32, 64);

    #pragma unroll
    for (int r = 0; r < 4; ++r) {
        float lr = __shfl(l_part, l4 * 4 + r, 64);   // lane q holds sum for query q
        float inv = 1.0f / lr;
        float* op = Ob + (size_t)(q0 + wave * 16 + l4 * 4 + r) * DH + l15;
        #pragma unroll
        for (int dt = 0; dt < 4; ++dt) op[dt * 16] = o_acc[dt][r] * inv;
    }
}

extern "C" void kernel_launch(void* const* d_in, const int* in_sizes, int n_in,
                              void* d_out, int out_size, void* d_ws, size_t ws_size,
                              hipStream_t stream) {
    const float* Q    = (const float*)d_in[0];
    const float* K    = (const float*)d_in[1];
    const float* V    = (const float*)d_in[2];
    const float* Bias = (const float*)d_in[3];
    float* O          = (float*)d_out;

    short* Kb = (short*)d_ws;                    // 8 MB
    short* Vt = Kb + (size_t)BHN * SEQ * DH;     // 8 MB

    prep_kv<<<dim3(BHN * 32), dim3(256), 0, stream>>>(K, V, Kb, Vt);
    mha_main<<<dim3(BHN * 32), dim3(256), 0, stream>>>(Q, Bias, Kb, Vt, O);
}

// Round 7
// 183.996 us; speedup vs baseline: 1.0007x; 1.0007x over previous
//
#include <hip/hip_runtime.h>
#include <hip/hip_bf16.h>

// Fused MHA fwd: out = softmax(scale*Q@K^T + bias) @ V
// B=2 H=16 S=2048 D=64, fp32 in/out, bf16 MFMA.
// R7 (= R6 fixed): reads-before-staging body with ONE __syncthreads() per
// tile. R6's NaN: manual "s_waitcnt vmcnt(4)" assumed the 4 newest vmem ops
// were the bias loads, but the backend may issue bias before staging ->
// retired the wrong group -> read unstaged LDS. __syncthreads (vmcnt 0) has
// no counting assumption, and since staging is issued AFTER all ds_reads,
// everything drained at the barrier is a full compute-phase old (cheap);
// staging(t+1) is in flight across QK+softmax+PV of tile t.
// Keeps: S^T trick + phi-permuted V (in-register P, no LDS round-trip),
// XOR-swizzled LDS (0 conflicts), bias prefetched one tile ahead.

#define SEQ 2048
#define DH  64
#define BHN 32
#define LOG2E 1.44269504088896f

typedef __attribute__((ext_vector_type(8))) short bf16x8;
typedef __attribute__((ext_vector_type(4))) float f32x4;
typedef __attribute__((ext_vector_type(8))) short short8v;

__device__ inline short f2b(float x) {
    union { float f; unsigned u; } v; v.f = x;
    unsigned r = v.u + 0x7fff + ((v.u >> 16) & 1);
    return (short)(r >> 16);
}

__device__ inline void gl_lds16(const void* g, void* l) {
    __builtin_amdgcn_global_load_lds(
        (const __attribute__((address_space(1))) void*)g,
        (__attribute__((address_space(3))) void*)l, 16, 0, 0);
}

// phi: PV A-frag slot rho' -> logical key offset within the 64-tile.
__device__ __host__ inline int phi(int r) {
    return 32 * (r >> 5) + 16 * ((r >> 2) & 1) + 4 * ((r >> 3) & 3) + (r & 3);
}

// ---- fused prep: K fp32->bf16 (identity) + V fp32->bf16 transposed with
// phi-permuted columns within each 64-column block ----
__global__ __launch_bounds__(256)
void prep_kv(const float* __restrict__ K, const float* __restrict__ V,
             short* __restrict__ Kb, short* __restrict__ Vt) {
    __shared__ short t[64 * 72];
    const int tid = threadIdx.x;
    const int bh = blockIdx.x >> 5, st = blockIdx.x & 31, s0 = st * 64;

    {
        const float* Kp = K + ((size_t)bh * SEQ + s0) * DH;
        short* Ko = Kb + ((size_t)bh * SEQ + s0) * DH;
        #pragma unroll
        for (int i = 0; i < 2; ++i) {
            size_t o = (size_t)(tid + i * 256) * 8;
            f32x4 a = *(const f32x4*)(Kp + o);
            f32x4 b = *(const f32x4*)(Kp + o + 4);
            short8v s;
            #pragma unroll
            for (int j = 0; j < 4; ++j) { s[j] = f2b(a[j]); s[4 + j] = f2b(b[j]); }
            *(short8v*)(Ko + o) = s;
        }
    }

    const float* Vb = V + (size_t)bh * SEQ * DH + (size_t)s0 * DH;
    #pragma unroll
    for (int i = 0; i < 4; ++i) {
        int c = tid + i * 256, s = c >> 4, c4 = c & 15;
        f32x4 v = *(const f32x4*)(Vb + s * DH + c4 * 4);
        #pragma unroll
        for (int j = 0; j < 4; ++j) t[s * 72 + c4 * 4 + j] = f2b(v[j]);
    }
    __syncthreads();
    // Vt[bh][d][s0 + rho'] = V[s0 + phi(rho')][d]
    const int d = tid >> 2, part = tid & 3;
    short* outp = Vt + (size_t)bh * DH * SEQ + (size_t)d * SEQ + s0 + part * 16;
    #pragma unroll
    for (int h = 0; h < 2; ++h) {
        short8v w;
        #pragma unroll
        for (int u = 0; u < 8; ++u) {
            int rho = part * 16 + h * 8 + u;
            w[u] = t[phi(rho) * 72 + d];
        }
        *(short8v*)(outp + h * 8) = w;
    }
}

// ---- main fused attention ----
__global__ __launch_bounds__(256, 4)
void mha_main(const float* __restrict__ Q, const float* __restrict__ Bias,
              const short* __restrict__ Kb, const short* __restrict__ Vt,
              float* __restrict__ Out)
{
    __shared__ short kA[64 * DH];
    __shared__ short kB[64 * DH];
    __shared__ short vA[64 * DH];
    __shared__ short vB[64 * DH];

    const int tid = threadIdx.x, lane = tid & 63, wave = tid >> 6;
    const int l15 = lane & 15, l4 = lane >> 4;
    const int qb = blockIdx.x & 31, bh = blockIdx.x >> 5;
    const int q0 = qb * 64;

    const float* Qb = Q + (size_t)bh * SEQ * DH;
    const short* Kh = Kb + (size_t)bh * SEQ * DH;
    const short* Vh = Vt + (size_t)bh * DH * SEQ;
    float* Ob = Out + (size_t)bh * SEQ * DH;

    // Q fragments (per-lane: query=l15, d=ks*32+l4*8+j), pre-scaled by LOG2E/8
    bf16x8 qf[2];
    {
        const float* qp = Qb + (size_t)(q0 + wave * 16 + l15) * DH;
        #pragma unroll
        for (int ks = 0; ks < 2; ++ks) {
            short tmp[8];
            #pragma unroll
            for (int j = 0; j < 8; ++j) tmp[j] = f2b(qp[ks * 32 + l4 * 8 + j] * (0.125f * LOG2E));
            qf[ks] = *reinterpret_cast<bf16x8*>(tmp);
        }
    }

    f32x4 o_acc[4];
    #pragma unroll
    for (int dt = 0; dt < 4; ++dt) o_acc[dt] = f32x4{0.f, 0.f, 0.f, 0.f};
    float l_part = 0.f;   // per-lane partial sum for query l15

    // staging descriptors: lane's fixed LDS slot, swizzled global chunk
    const short *kg0, *kg1, *vg0, *vg1;
    int off0, off1;
    {
        int s0_ = wave * 64 + lane, r0 = s0_ >> 3, c0 = s0_ & 7, g0 = c0 ^ (r0 & 7);
        int s1_ = 256 + wave * 64 + lane, r1 = s1_ >> 3, c1 = s1_ & 7, g1 = c1 ^ (r1 & 7);
        kg0 = Kh + (size_t)r0 * DH + g0 * 8;
        vg0 = Vh + (size_t)r0 * SEQ + g0 * 8;
        kg1 = Kh + (size_t)r1 * DH + g1 * 8;
        vg1 = Vh + (size_t)r1 * SEQ + g1 * 8;
        off0 = (wave * 64) * 8;
        off1 = (256 + wave * 64) * 8;
    }
    const float* bp0 = Bias + (size_t)(q0 + wave * 16 + l15) * SEQ + l4 * 4;
    const int swz = l15 & 7;

    // preamble: stage tile 0 into A; load bias tile 0
    gl_lds16(kg0, kA + off0);
    gl_lds16(kg1, kA + off1);
    gl_lds16(vg0, vA + off0);
    gl_lds16(vg1, vA + off1);
    f32x4 bv[4];
    #pragma unroll
    for (int nt = 0; nt < 4; ++nt)
        bv[nt] = *(const f32x4*)(bp0 + nt * 16);

    auto body = [&](int kt, const short* kc, const short* vc,
                    short* knx, short* vnx) {
        // Single rendezvous: drains THIS tile's staging (issued a full
        // compute-phase ago) + syncs waves. No vmcnt counting games.
        __syncthreads();

        // --- ALL LDS reads for this tile, before any new staging ---
        bf16x8 kfr[2][4];
        #pragma unroll
        for (int ks = 0; ks < 2; ++ks)
            #pragma unroll
            for (int nt = 0; nt < 4; ++nt) {
                int cc = (ks * 4 + l4) ^ swz;
                kfr[ks][nt] = *(const bf16x8*)&kc[(nt * 16 + l15) * DH + cc * 8];
            }
        bf16x8 vfr[2][4];
        #pragma unroll
        for (int ks = 0; ks < 2; ++ks)
            #pragma unroll
            for (int dt = 0; dt < 4; ++dt) {
                int cc = (ks * 4 + l4) ^ swz;
                vfr[ks][dt] = *(const bf16x8*)&vc[(dt * 16 + l15) * DH + cc * 8];
            }

        // --- stage tile kt+1 (after all ds_reads; in flight across compute) ---
        const int kn = (kt + 1) & 31;
        gl_lds16(kg0 + (size_t)kn * 64 * DH, knx + off0);
        gl_lds16(kg1 + (size_t)kn * 64 * DH, knx + off1);
        gl_lds16(vg0 + kn * 64, vnx + off0);
        gl_lds16(vg1 + kn * 64, vnx + off1);

        // S^T = K*Q^T (lane holds S^T[key=nt*16+l4*4+r][query=l15], log2-scaled)
        f32x4 sacc[4];
        #pragma unroll
        for (int nt = 0; nt < 4; ++nt) sacc[nt] = f32x4{0.f, 0.f, 0.f, 0.f};
        #pragma unroll
        for (int ks = 0; ks < 2; ++ks)
            #pragma unroll
            for (int nt = 0; nt < 4; ++nt)
                sacc[nt] = __builtin_amdgcn_mfma_f32_16x16x32_bf16(kfr[ks][nt], qf[ks], sacc[nt], 0, 0, 0);

        // softmax in log2 domain; pack -> PV A-frags in-register
        unsigned pk[4][2];
        #pragma unroll
        for (int nt = 0; nt < 4; ++nt) {
            float pv[4];
            #pragma unroll
            for (int r = 0; r < 4; ++r) {
                pv[r] = __builtin_amdgcn_exp2f(__builtin_fmaf(bv[nt][r], LOG2E, sacc[nt][r]));
                l_part += pv[r];
            }
            #pragma unroll
            for (int rp = 0; rp < 2; ++rp) {
                __hip_bfloat162 h2 = __float22bfloat162_rn(float2{pv[2 * rp], pv[2 * rp + 1]});
                pk[nt][rp] = *reinterpret_cast<unsigned*>(&h2);
            }
        }

        // bias prefetch for tile kt+1 (bv consumed above)
        {
            const float* bp = bp0 + kn * 64;
            #pragma unroll
            for (int nt = 0; nt < 4; ++nt)
                bv[nt] = *(const f32x4*)(bp + nt * 16);
        }

        // O += P @ V_staged (phi-permuted V makes pk the A-frags directly)
        #pragma unroll
        for (int ks = 0; ks < 2; ++ks) {
            union { bf16x8 v; unsigned u[4]; } af;
            af.u[0] = pk[2 * ks][0]; af.u[1] = pk[2 * ks][1];
            af.u[2] = pk[2 * ks + 1][0]; af.u[3] = pk[2 * ks + 1][1];
            #pragma unroll
            for (int dt = 0; dt < 4; ++dt)
                o_acc[dt] = __builtin_amdgcn_mfma_f32_16x16x32_bf16(af.v, vfr[ks][dt], o_acc[dt], 0, 0, 0);
        }
    };

    for (int kt = 0; kt < SEQ / 64; kt += 2) {
        body(kt,     kA, vA, kB, vB);
        body(kt + 1, kB, vB, kA, vA);
    }

    // l: full sum per query l15 (reduce across l4 groups), then fetch per-row
    l_part += __shfl_xor(l_part, 16, 64);
    l_part += __shfl_xor(l_part, 32, 64);

    #pragma unroll
    for (int r = 0; r < 4; ++r) {
        float lr = __shfl(l_part, l4 * 4 + r, 64);
        float inv = 1.0f / lr;
        float* op = Ob + (size_t)(q0 + wave * 16 + l4 * 4 + r) * DH + l15;
        #pragma unroll
        for (int dt = 0; dt < 4; ++dt) op[dt * 16] = o_acc[dt][r] * inv;
    }
}

extern "C" void kernel_launch(void* const* d_in, const int* in_sizes, int n_in,
                              void* d_out, int out_size, void* d_ws, size_t ws_size,
                              hipStream_t stream) {
    const float* Q    = (const float*)d_in[0];
    const float* K    = (const float*)d_in[1];
    const float* V    = (const float*)d_in[2];
    const float* Bias = (const float*)d_in[3];
    float* O          = (float*)d_out;

    short* Kb = (short*)d_ws;                    // 8 MB
    short* Vt = Kb + (size_t)BHN * SEQ * DH;     // 8 MB

    prep_kv<<<dim3(BHN * 32), dim3(256), 0, stream>>>(K, V, Kb, Vt);
    mha_main<<<dim3(BHN * 32), dim3(256), 0, stream>>>(Q, Bias, Kb, Vt, O);
}

// Round 8
// 171.229 us; speedup vs baseline: 1.0753x; 1.0746x over previous
//
#include <hip/hip_runtime.h>
#include <hip/hip_bf16.h>

// Fused MHA fwd: out = softmax(scale*Q@K^T + bias) @ V
// B=2 H=16 S=2048 D=64, fp32 in/out, bf16 MFMA.
// R8: TM=128 — each wave serves TWO 16-query fragment groups per K/V tile.
// R7 post-mortem: no pipe >50% busy -> latency/dependency-bound, not
// pipe-bound. Doubling MFMA work per LDS read (K/V frags reused across both
// query groups) doubles independent MFMA chains per phase, halves barriers
// and wave-tiles. Keeps: S^T trick + phi-permuted V (in-register P),
// XOR-swizzled LDS (0 conflicts), reads-before-staging single-barrier body.

#define SEQ 2048
#define DH  64
#define BHN 32
#define LOG2E 1.44269504088896f

typedef __attribute__((ext_vector_type(8))) short bf16x8;
typedef __attribute__((ext_vector_type(4))) float f32x4;
typedef __attribute__((ext_vector_type(8))) short short8v;

__device__ inline short f2b(float x) {
    union { float f; unsigned u; } v; v.f = x;
    unsigned r = v.u + 0x7fff + ((v.u >> 16) & 1);
    return (short)(r >> 16);
}

__device__ inline void gl_lds16(const void* g, void* l) {
    __builtin_amdgcn_global_load_lds(
        (const __attribute__((address_space(1))) void*)g,
        (__attribute__((address_space(3))) void*)l, 16, 0, 0);
}

// phi: PV A-frag slot rho' -> logical key offset within the 64-tile.
__device__ __host__ inline int phi(int r) {
    return 32 * (r >> 5) + 16 * ((r >> 2) & 1) + 4 * ((r >> 3) & 3) + (r & 3);
}

// ---- fused prep: K fp32->bf16 (identity) + V fp32->bf16 transposed with
// phi-permuted columns within each 64-column block ----
__global__ __launch_bounds__(256)
void prep_kv(const float* __restrict__ K, const float* __restrict__ V,
             short* __restrict__ Kb, short* __restrict__ Vt) {
    __shared__ short t[64 * 72];
    const int tid = threadIdx.x;
    const int bh = blockIdx.x >> 5, st = blockIdx.x & 31, s0 = st * 64;

    {
        const float* Kp = K + ((size_t)bh * SEQ + s0) * DH;
        short* Ko = Kb + ((size_t)bh * SEQ + s0) * DH;
        #pragma unroll
        for (int i = 0; i < 2; ++i) {
            size_t o = (size_t)(tid + i * 256) * 8;
            f32x4 a = *(const f32x4*)(Kp + o);
            f32x4 b = *(const f32x4*)(Kp + o + 4);
            short8v s;
            #pragma unroll
            for (int j = 0; j < 4; ++j) { s[j] = f2b(a[j]); s[4 + j] = f2b(b[j]); }
            *(short8v*)(Ko + o) = s;
        }
    }

    const float* Vb = V + (size_t)bh * SEQ * DH + (size_t)s0 * DH;
    #pragma unroll
    for (int i = 0; i < 4; ++i) {
        int c = tid + i * 256, s = c >> 4, c4 = c & 15;
        f32x4 v = *(const f32x4*)(Vb + s * DH + c4 * 4);
        #pragma unroll
        for (int j = 0; j < 4; ++j) t[s * 72 + c4 * 4 + j] = f2b(v[j]);
    }
    __syncthreads();
    // Vt[bh][d][s0 + rho'] = V[s0 + phi(rho')][d]
    const int d = tid >> 2, part = tid & 3;
    short* outp = Vt + (size_t)bh * DH * SEQ + (size_t)d * SEQ + s0 + part * 16;
    #pragma unroll
    for (int h = 0; h < 2; ++h) {
        short8v w;
        #pragma unroll
        for (int u = 0; u < 8; ++u) {
            int rho = part * 16 + h * 8 + u;
            w[u] = t[phi(rho) * 72 + d];
        }
        *(short8v*)(outp + h * 8) = w;
    }
}

// ---- main fused attention: 128 queries/block, 32 per wave (2 groups) ----
__global__ __launch_bounds__(256, 2)
void mha_main(const float* __restrict__ Q, const float* __restrict__ Bias,
              const short* __restrict__ Kb, const short* __restrict__ Vt,
              float* __restrict__ Out)
{
    __shared__ short kA[64 * DH];
    __shared__ short kB[64 * DH];
    __shared__ short vA[64 * DH];
    __shared__ short vB[64 * DH];

    const int tid = threadIdx.x, lane = tid & 63, wave = tid >> 6;
    const int l15 = lane & 15, l4 = lane >> 4;
    const int qb = blockIdx.x & 15, bh = blockIdx.x >> 4;
    const int q0 = qb * 128;

    const float* Qb = Q + (size_t)bh * SEQ * DH;
    const short* Kh = Kb + (size_t)bh * SEQ * DH;
    const short* Vh = Vt + (size_t)bh * DH * SEQ;
    float* Ob = Out + (size_t)bh * SEQ * DH;

    // Q fragments for both groups (query = q0+wave*32+g*16+l15), scaled LOG2E/8
    bf16x8 qf[2][2];
    #pragma unroll
    for (int g = 0; g < 2; ++g) {
        const float* qp = Qb + (size_t)(q0 + wave * 32 + g * 16 + l15) * DH;
        #pragma unroll
        for (int ks = 0; ks < 2; ++ks) {
            short tmp[8];
            #pragma unroll
            for (int j = 0; j < 8; ++j) tmp[j] = f2b(qp[ks * 32 + l4 * 8 + j] * (0.125f * LOG2E));
            qf[g][ks] = *reinterpret_cast<bf16x8*>(tmp);
        }
    }

    f32x4 o_acc[2][4];
    #pragma unroll
    for (int g = 0; g < 2; ++g)
        #pragma unroll
        for (int dt = 0; dt < 4; ++dt) o_acc[g][dt] = f32x4{0.f, 0.f, 0.f, 0.f};
    float l_part[2] = {0.f, 0.f};

    // staging descriptors: lane's fixed LDS slot, swizzled global chunk
    const short *kg0, *kg1, *vg0, *vg1;
    int off0, off1;
    {
        int s0_ = wave * 64 + lane, r0 = s0_ >> 3, c0 = s0_ & 7, g0 = c0 ^ (r0 & 7);
        int s1_ = 256 + wave * 64 + lane, r1 = s1_ >> 3, c1 = s1_ & 7, g1 = c1 ^ (r1 & 7);
        kg0 = Kh + (size_t)r0 * DH + g0 * 8;
        vg0 = Vh + (size_t)r0 * SEQ + g0 * 8;
        kg1 = Kh + (size_t)r1 * DH + g1 * 8;
        vg1 = Vh + (size_t)r1 * SEQ + g1 * 8;
        off0 = (wave * 64) * 8;
        off1 = (256 + wave * 64) * 8;
    }
    const float* bpg[2];
    #pragma unroll
    for (int g = 0; g < 2; ++g)
        bpg[g] = Bias + (size_t)(q0 + wave * 32 + g * 16 + l15) * SEQ + l4 * 4;
    const int swz = l15 & 7;

    // preamble: stage tile 0 into A; load bias tile 0 (both groups)
    gl_lds16(kg0, kA + off0);
    gl_lds16(kg1, kA + off1);
    gl_lds16(vg0, vA + off0);
    gl_lds16(vg1, vA + off1);
    f32x4 bv[2][4];
    #pragma unroll
    for (int g = 0; g < 2; ++g)
        #pragma unroll
        for (int nt = 0; nt < 4; ++nt)
            bv[g][nt] = *(const f32x4*)(bpg[g] + nt * 16);

    auto body = [&](int kt, const short* kc, const short* vc,
                    short* knx, short* vnx) {
        __syncthreads();   // drains this tile's staging (a full phase old)

        // --- ALL LDS reads, before new staging ---
        bf16x8 kfr[2][4];
        #pragma unroll
        for (int ks = 0; ks < 2; ++ks)
            #pragma unroll
            for (int nt = 0; nt < 4; ++nt) {
                int cc = (ks * 4 + l4) ^ swz;
                kfr[ks][nt] = *(const bf16x8*)&kc[(nt * 16 + l15) * DH + cc * 8];
            }
        bf16x8 vfr[2][4];
        #pragma unroll
        for (int ks = 0; ks < 2; ++ks)
            #pragma unroll
            for (int dt = 0; dt < 4; ++dt) {
                int cc = (ks * 4 + l4) ^ swz;
                vfr[ks][dt] = *(const bf16x8*)&vc[(dt * 16 + l15) * DH + cc * 8];
            }

        // --- stage tile kt+1 ---
        const int kn = (kt + 1) & 31;
        gl_lds16(kg0 + (size_t)kn * 64 * DH, knx + off0);
        gl_lds16(kg1 + (size_t)kn * 64 * DH, knx + off1);
        gl_lds16(vg0 + kn * 64, vnx + off0);
        gl_lds16(vg1 + kn * 64, vnx + off1);

        // S^T = K*Q^T for both groups: 16 MFMAs, 8 independent chains
        f32x4 sacc[2][4];
        #pragma unroll
        for (int g = 0; g < 2; ++g)
            #pragma unroll
            for (int nt = 0; nt < 4; ++nt) sacc[g][nt] = f32x4{0.f, 0.f, 0.f, 0.f};
        #pragma unroll
        for (int ks = 0; ks < 2; ++ks)
            #pragma unroll
            for (int nt = 0; nt < 4; ++nt)
                #pragma unroll
                for (int g = 0; g < 2; ++g)
                    sacc[g][nt] = __builtin_amdgcn_mfma_f32_16x16x32_bf16(
                        kfr[ks][nt], qf[g][ks], sacc[g][nt], 0, 0, 0);

        // softmax (log2 domain) + pack -> PV A-frags, both groups
        unsigned pk[2][4][2];
        #pragma unroll
        for (int g = 0; g < 2; ++g)
            #pragma unroll
            for (int nt = 0; nt < 4; ++nt) {
                float pv[4];
                #pragma unroll
                for (int r = 0; r < 4; ++r) {
                    pv[r] = __builtin_amdgcn_exp2f(__builtin_fmaf(bv[g][nt][r], LOG2E, sacc[g][nt][r]));
                    l_part[g] += pv[r];
                }
                #pragma unroll
                for (int rp = 0; rp < 2; ++rp) {
                    __hip_bfloat162 h2 = __float22bfloat162_rn(float2{pv[2 * rp], pv[2 * rp + 1]});
                    pk[g][nt][rp] = *reinterpret_cast<unsigned*>(&h2);
                }
            }

        // bias prefetch for tile kt+1
        #pragma unroll
        for (int g = 0; g < 2; ++g) {
            const float* bp = bpg[g] + kn * 64;
            #pragma unroll
            for (int nt = 0; nt < 4; ++nt)
                bv[g][nt] = *(const f32x4*)(bp + nt * 16);
        }

        // O += P @ V_staged: 16 MFMAs, 8 independent chains
        #pragma unroll
        for (int ks = 0; ks < 2; ++ks)
            #pragma unroll
            for (int g = 0; g < 2; ++g) {
                union { bf16x8 v; unsigned u[4]; } af;
                af.u[0] = pk[g][2 * ks][0];     af.u[1] = pk[g][2 * ks][1];
                af.u[2] = pk[g][2 * ks + 1][0]; af.u[3] = pk[g][2 * ks + 1][1];
                #pragma unroll
                for (int dt = 0; dt < 4; ++dt)
                    o_acc[g][dt] = __builtin_amdgcn_mfma_f32_16x16x32_bf16(
                        af.v, vfr[ks][dt], o_acc[g][dt], 0, 0, 0);
            }
    };

    for (int kt = 0; kt < SEQ / 64; kt += 2) {
        body(kt,     kA, vA, kB, vB);
        body(kt + 1, kB, vB, kA, vA);
    }

    // epilogue per group: l reduce + scaled store
    #pragma unroll
    for (int g = 0; g < 2; ++g) {
        float s = l_part[g];
        s += __shfl_xor(s, 16, 64);
        s += __shfl_xor(s, 32, 64);
        #pragma unroll
        for (int r = 0; r < 4; ++r) {
            float lr = __shfl(s, l4 * 4 + r, 64);
            float inv = 1.0f / lr;
            float* op = Ob + (size_t)(q0 + wave * 32 + g * 16 + l4 * 4 + r) * DH + l15;
            #pragma unroll
            for (int dt = 0; dt < 4; ++dt) op[dt * 16] = o_acc[g][dt][r] * inv;
        }
    }
}

extern "C" void kernel_launch(void* const* d_in, const int* in_sizes, int n_in,
                              void* d_out, int out_size, void* d_ws, size_t ws_size,
                              hipStream_t stream) {
    const float* Q    = (const float*)d_in[0];
    const float* K    = (const float*)d_in[1];
    const float* V    = (const float*)d_in[2];
    const float* Bias = (const float*)d_in[3];
    float* O          = (float*)d_out;

    short* Kb = (short*)d_ws;                    // 8 MB
    short* Vt = Kb + (size_t)BHN * SEQ * DH;     // 8 MB

    prep_kv<<<dim3(BHN * 32), dim3(256), 0, stream>>>(K, V, Kb, Vt);
    mha_main<<<dim3(BHN * 16), dim3(256), 0, stream>>>(Q, Bias, Kb, Vt, O);
}